// Round 12
// baseline (100.618 us; speedup 1.0000x reference)
//
#include <hip/hip_runtime.h>
#include <stdint.h>

// E8P 256-codeword quantizer, analytic decode. Round 8 kernel (fifth
// resubmit — consecutive GPU-acquisition timeouts; never yet run):
// PPT=1 (minimal live set) + forced occupancy via __launch_bounds__(256, 8)
// (target <=64 VGPR, 8 waves/SIMD) + arithmetic Xq reconstruction
// (verified absmax==0 in r7).
// Theory: decode is latency-bound at low TLP; doubling resident waves covers
// the load->decode->table->merge dependency chain.
//
// Codebook: idx 0..112 integer (zero + +-e_i+-e_j), 113..240 half (+-0.5,
// even #neg), 241..255 extra (5 bases x tails{5,6,7}).
// Near-tie guard (tau=6.4e-5 or any x_d==0): wave-cooperative rescore,
// bit-identical to the round-1 brute force; those lanes gather grid[bidx].

#define DIM 8
#define NCODES 256

struct Tables {
    unsigned char pair_idx[256]; // [((lo*8+hi)*2+neg_lo)*2+neg_hi]
    unsigned char half_idx[256]; // [negmask]; even-parity entries valid
    unsigned char zero_idx;
};

constexpr Tables make_tables() {
    Tables t{};
    // ---- integer block: zero + 112 pair points, ranked by lex digit key ----
    unsigned key[113] = {};
    int pi[113] = {}, pj[113] = {}, psi[113] = {}, psj[113] = {};
    int n = 0;
    { // zero vector: all digits 2 (value 0)
        unsigned k = 0;
        for (int d = 0; d < 8; ++d) k = k * 4u + 2u;
        key[n] = k; pi[n] = -1; pj[n] = -1; psi[n] = 0; psj[n] = 0; ++n;
    }
    for (int i = 0; i < 8; ++i)
        for (int j = i + 1; j < 8; ++j)
            for (int a = 0; a < 2; ++a)       // a=1 -> coord i is -1 (digit 1), else +1 (digit 3)
                for (int b = 0; b < 2; ++b) {
                    unsigned k = 0;
                    for (int d = 0; d < 8; ++d) {
                        unsigned dig = 2u;
                        if (d == i) dig = a ? 1u : 3u;
                        if (d == j) dig = b ? 1u : 3u;
                        k = k * 4u + dig;
                    }
                    key[n] = k; pi[n] = i; pj[n] = j; psi[n] = a; psj[n] = b; ++n;
                }
    for (int p = 1; p < n; ++p) { // insertion sort by key
        unsigned kk = key[p]; int a = pi[p], b = pj[p], c = psi[p], d2 = psj[p];
        int q = p - 1;
        while (q >= 0 && key[q] > kk) {
            key[q+1]=key[q]; pi[q+1]=pi[q]; pj[q+1]=pj[q]; psi[q+1]=psi[q]; psj[q+1]=psj[q]; --q;
        }
        key[q+1]=kk; pi[q+1]=a; pj[q+1]=b; psi[q+1]=c; psj[q+1]=d2;
    }
    for (int r = 0; r < n; ++r) {
        if (pi[r] < 0) t.zero_idx = (unsigned char)r;
        else t.pair_idx[(((pi[r]*8 + pj[r])*2 + psi[r])*2) + psj[r]] = (unsigned char)r;
    }
    // ---- half block: even-popcount sign masks, digit neg->1, pos->2 ----
    unsigned hkey[128] = {}; int hm[128] = {}; int hn = 0;
    for (int m = 0; m < 256; ++m) {
        int pc = 0; for (int d = 0; d < 8; ++d) pc += (m >> d) & 1;
        if (pc & 1) continue;
        unsigned k = 0;
        for (int d = 0; d < 8; ++d) k = k * 4u + (((m >> d) & 1) ? 1u : 2u);
        hkey[hn] = k; hm[hn] = m; ++hn;
    }
    for (int p = 1; p < hn; ++p) {
        unsigned kk = hkey[p]; int mm = hm[p]; int q = p - 1;
        while (q >= 0 && hkey[q] > kk) { hkey[q+1]=hkey[q]; hm[q+1]=hm[q]; --q; }
        hkey[q+1]=kk; hm[q+1]=mm;
    }
    for (int r = 0; r < hn; ++r) t.half_idx[hm[r]] = (unsigned char)(113 + r);
    return t;
}

constexpr Tables h_tab = make_tables();
__constant__ Tables g_tab = h_tab;

// MODE: 0 = Xq only; 1 = idx as uint8 bytes after Xq; 2 = idx as float after Xq
template <int MODE>
__global__ __launch_bounds__(256, 8)
void e8_decode_kernel(const float* __restrict__ X,
                      const float* __restrict__ grid,
                      const float* __restrict__ gnorm,
                      float* __restrict__ xq_out,
                      void* __restrict__ idx_out,
                      int N)
{
    const int pt = blockIdx.x * blockDim.x + threadIdx.x;
    if (pt >= N) return;
    const int lane = threadIdx.x & 63;

    const float4* xsrc = reinterpret_cast<const float4*>(X + (size_t)pt * DIM);
    const float4 xa = xsrc[0];
    const float4 xb = xsrc[1];
    float x[8] = {xa.x, xa.y, xa.z, xa.w, xb.x, xb.y, xb.z, xb.w};

    float a[8]; uint32_t sb[8];
    #pragma unroll
    for (int d = 0; d < 8; ++d) {
        const uint32_t u = __float_as_uint(x[d]);
        sb[d] = u >> 31;
        a[d] = __uint_as_float(u & 0x7fffffffu);
    }
    uint32_t mask = 0, par = 0;
    #pragma unroll
    for (int d = 0; d < 8; ++d) { mask |= sb[d] << d; par ^= sb[d]; }
    const bool odd = (par != 0);

    // sequential sum of |x|
    float S = a[0];
    #pragma unroll
    for (int d = 1; d < 8; ++d) S += a[d];

    // min + argmin (first occurrence wins)
    float mn = a[0]; int mi = 0;
    #pragma unroll
    for (int d = 1; d < 8; ++d) { const bool lt = a[d] < mn; mn = lt ? a[d] : mn; mi = lt ? d : mi; }
    float mn2 = 3.0e38f;
    #pragma unroll
    for (int d = 0; d < 8; ++d) { const float v = (d == mi) ? 3.0e38f : a[d]; mn2 = fminf(mn2, v); }

    // top-3 of |x| (indices for top-2)
    float m1 = a[0]; int i1 = 0;
    #pragma unroll
    for (int d = 1; d < 8; ++d) { const bool gt = a[d] > m1; m1 = gt ? a[d] : m1; i1 = gt ? d : i1; }
    float m2 = -3.0e38f; int i2 = 0;
    #pragma unroll
    for (int d = 0; d < 8; ++d) {
        const float v = (d == i1) ? -3.0e38f : a[d];
        const bool gt = v > m2; m2 = gt ? v : m2; i2 = gt ? d : i2;
    }
    float m3 = -3.0e38f;
    #pragma unroll
    for (int d = 0; d < 8; ++d) {
        const float v = (d == i1 || d == i2) ? -3.0e38f : a[d];
        m3 = fmaxf(m3, v);
    }

    // ---- class champion scores (identical expressions to rounds 2-7) ----
    const float s_pair = fmaf(2.0f, m1 + m2, -2.0f);
    const float s_half = odd ? (fmaf(-2.0f, mn, S) - 2.0f) : (S - 2.0f);

    const float y01 = x[0] + x[1];
    float b[5];
    b[0] = y01 + x[2];            // {0,1,2}
    b[1] = y01 + x[4];            // {0,1,4}
    b[2] = (x[0] + x[3]) + x[4];  // {0,3,4}
    b[3] = (x[2] + x[3]) + x[4];  // {2,3,4}
    b[4] = (x[1] + x[2]) + x[3];  // {1,2,3}
    float bm = b[0]; int bi = 0;
    #pragma unroll
    for (int k = 1; k < 5; ++k) { const bool gt = b[k] > bm; bm = gt ? b[k] : bm; bi = gt ? k : bi; }
    float b2nd = -3.0e38f;
    #pragma unroll
    for (int k = 0; k < 5; ++k) { const float v = (k == bi) ? -3.0e38f : b[k]; b2nd = fmaxf(b2nd, v); }
    float tm = x[5]; int ti = 0;
    { const bool gt = x[6] > tm; tm = gt ? x[6] : tm; ti = gt ? 1 : ti; }
    { const bool gt = x[7] > tm; tm = gt ? x[7] : tm; ti = gt ? 2 : ti; }
    const float t2 = fmaxf(fminf(fmaxf(x[5], x[6]), x[7]), fminf(x[5], x[6])); // median of 3
    const float s_extra = fmaf(2.0f, bm + tm, -4.0f);

    // ---- within-class runner-ups for the tie guard ----
    const float r_pair  = fmaf(2.0f, m1 + m3, -2.0f);
    const float r_half  = odd ? (fmaf(-2.0f, mn2, S) - 2.0f)
                              : (fmaf(-2.0f, mn + mn2, S) - 2.0f);
    const float r_extra = fmaf(2.0f, fmaxf(b2nd + tm, bm + t2), -4.0f);

    // ---- codeword indices + reconstruction parameters ----
    const int lo = (i1 < i2) ? i1 : i2;
    const int hi = (i1 < i2) ? i2 : i1;
    const uint32_t slo = (mask >> lo) & 1u;
    const uint32_t shi = (mask >> hi) & 1u;
    const int idx_pair  = g_tab.pair_idx[(((lo << 3) + hi) << 2) + (int)((slo << 1) | shi)];
    const uint32_t hmask = odd ? (mask ^ (1u << mi)) : mask;
    const int idx_half  = g_tab.half_idx[hmask & 255u];
    const int idx_extra = 241 + ti * 5 + bi;
    const int idx_zero  = g_tab.zero_idx;
    // extra-row support mask: base {0,1,2}/{0,1,4}/{0,3,4}/{2,3,4}/{1,2,3} + tail bit
    const uint32_t emask = (uint32_t)((0x0E1C191307ULL >> (bi * 8)) & 0xFFu)
                         | (1u << (5 + ti));

    // ---- merge 4 candidates; track best/second-best and winning class ----
    float best = s_pair; int bidx = idx_pair; int cls = 0; float sec = -3.0e38f;
    {
        const float s = 0.0f; const int id = idx_zero;
        const bool gt = s > best;
        const bool take = gt || (s == best && id < bidx);
        sec = fmaxf(sec, gt ? best : s);
        best = gt ? s : best;
        bidx = take ? id : bidx;
        cls  = take ? 1 : cls;
    }
    {
        const float s = s_half; const int id = idx_half;
        const bool gt = s > best;
        const bool take = gt || (s == best && id < bidx);
        sec = fmaxf(sec, gt ? best : s);
        best = gt ? s : best;
        bidx = take ? id : bidx;
        cls  = take ? 2 : cls;
    }
    {
        const float s = s_extra; const int id = idx_extra;
        const bool gt = s > best;
        const bool take = gt || (s == best && id < bidx);
        sec = fmaxf(sec, gt ? best : s);
        best = gt ? s : best;
        bidx = take ? id : bidx;
        cls  = take ? 3 : cls;
    }
    sec = fmaxf(fmaxf(sec, r_pair), fmaxf(r_half, r_extra));

    // ---- near-tie / degenerate guard: wave-cooperative rescore ----
    const bool fb = !((best - sec) > 6.4e-5f) || !(mn > 0.0f);
    uint64_t bal = __ballot(fb);
    while (bal) {
        const int src = __ffsll((unsigned long long)bal) - 1;
        bal &= bal - 1;
        float xs[8];
        #pragma unroll
        for (int d = 0; d < 8; ++d) xs[d] = __shfl(x[d], src);
        float2 xv[4];
        #pragma unroll
        for (int q = 0; q < 4; ++q)
            xv[q] = make_float2(2.0f * xs[2*q], 2.0f * xs[2*q + 1]);
        float bb = -3.4e38f; int bbi = 0;
        #pragma unroll
        for (int u = 0; u < 4; ++u) {   // c = lane*4+u, bit-identical scoring
            const int c = (lane << 2) + u;
            const float2* g2 = reinterpret_cast<const float2*>(grid + c * DIM);
            float2 acc = xv[0] * g2[0];
            acc += xv[1] * g2[1];
            acc += xv[2] * g2[2];
            acc += xv[3] * g2[3];
            const float s = (acc.x + acc.y) - gnorm[c];
            const bool gt = s > bb;
            bb = gt ? s : bb; bbi = gt ? c : bbi;
        }
        #pragma unroll
        for (int off = 32; off >= 1; off >>= 1) {  // lower index wins ties
            const float so = __shfl_xor(bb, off);
            const int   io = __shfl_xor(bbi, off);
            const bool take = (so > bb) || (so == bb && io < bbi);
            bb  = take ? so : bb;
            bbi = take ? io : bbi;
        }
        if (lane == src) bidx = bbi;
    }

    // ---- arithmetic Xq reconstruction (exact: values are +-1/+-0.5/0/1) ----
    uint32_t M    = (1u << lo) | (1u << hi);
    uint32_t base = 0x3F800000u;
    uint32_t smask = mask;
    if (cls == 1) { M = 0u; }
    if (cls == 2) { M = 0xFFu; base = 0x3F000000u; smask = hmask; }
    if (cls == 3) { M = emask; base = 0x3F800000u; smask = 0u; }

    uint32_t bits[8];
    #pragma unroll
    for (int d = 0; d < 8; ++d) {
        const uint32_t mb = (M >> d) & 1u;
        const uint32_t sg = ((smask >> d) & 1u) << 31;
        bits[d] = mb ? (base | sg) : 0u;
    }
    float4 q0 = make_float4(__uint_as_float(bits[0]), __uint_as_float(bits[1]),
                            __uint_as_float(bits[2]), __uint_as_float(bits[3]));
    float4 q1 = make_float4(__uint_as_float(bits[4]), __uint_as_float(bits[5]),
                            __uint_as_float(bits[6]), __uint_as_float(bits[7]));
    if (fb) {  // rare: rescored lanes take the true grid row
        const float4* gr = reinterpret_cast<const float4*>(grid + (size_t)bidx * DIM);
        q0 = gr[0];
        q1 = gr[1];
    }

    // ---- outputs ----
    float4* dst = reinterpret_cast<float4*>(xq_out + (size_t)pt * DIM);
    dst[0] = q0;
    dst[1] = q1;
    if (MODE == 2) {
        reinterpret_cast<float*>(idx_out)[pt] = (float)bidx;
    } else if (MODE == 1) {
        reinterpret_cast<uint8_t*>(idx_out)[pt] = (uint8_t)bidx;
    }
}

extern "C" void kernel_launch(void* const* d_in, const int* in_sizes, int n_in,
                              void* d_out, int out_size, void* d_ws, size_t ws_size,
                              hipStream_t stream)
{
    const float* X     = (const float*)d_in[0];
    const float* grid  = (const float*)d_in[1];
    const float* gnorm = (const float*)d_in[2];

    const int N = in_sizes[0] / DIM;

    float* xq   = (float*)d_out;
    void*  idxp = (void*)(xq + (size_t)N * DIM);

    const int blocks = (N + 255) / 256;

    const long xq_elems = (long)N * DIM;
    if ((long)out_size >= xq_elems + N) {
        e8_decode_kernel<2><<<blocks, 256, 0, stream>>>(X, grid, gnorm, xq, idxp, N);
    } else if ((long)out_size > xq_elems) {
        e8_decode_kernel<1><<<blocks, 256, 0, stream>>>(X, grid, gnorm, xq, idxp, N);
    } else {
        e8_decode_kernel<0><<<blocks, 256, 0, stream>>>(X, grid, gnorm, xq, idxp, N);
    }
}

// Round 13
// 87.914 us; speedup vs baseline: 1.1445x; 1.1445x over previous
//
#include <hip/hip_runtime.h>
#include <stdint.h>

// E8P 256-codeword quantizer, analytic decode. Round 13: rollback to the
// round-4 structure (best measured, session-normalized ~23us: PPT=1, gather
// output, wave-coop fallback, no launch-bounds override) + ONE change:
// NON-TEMPORAL stores for Xq/idx. Outputs (37.7 MB) are never re-read
// on-device; nt stores stop them displacing X (32 MB) from the 32 MB L2,
// cutting X re-fetch from HBM.
//
// Falsified so far: straggler tail (fixed r4), load-issue-bound (r7 PPT=4
// neutral), low-TLP latency-bound (r12 forced 8 waves/SIMD neutral/negative).
//
// Codebook: idx 0..112 integer (zero + +-e_i+-e_j), 113..240 half (+-0.5,
// even #neg), 241..255 extra (5 bases x tails{5,6,7}).
// Near-tie guard (tau=6.4e-5 or any x_d==0): wave-cooperative rescore,
// bit-identical to the round-1 brute force (absmax==0 verified r2-r4,r7,r12).

#define DIM 8
#define NCODES 256

typedef float vfloat4 __attribute__((ext_vector_type(4)));

struct Tables {
    unsigned char pair_idx[256]; // [((lo*8+hi)*2+neg_lo)*2+neg_hi]
    unsigned char half_idx[256]; // [negmask]; even-parity entries valid
    unsigned char zero_idx;
};

constexpr Tables make_tables() {
    Tables t{};
    // ---- integer block: zero + 112 pair points, ranked by lex digit key ----
    unsigned key[113] = {};
    int pi[113] = {}, pj[113] = {}, psi[113] = {}, psj[113] = {};
    int n = 0;
    { // zero vector: all digits 2 (value 0)
        unsigned k = 0;
        for (int d = 0; d < 8; ++d) k = k * 4u + 2u;
        key[n] = k; pi[n] = -1; pj[n] = -1; psi[n] = 0; psj[n] = 0; ++n;
    }
    for (int i = 0; i < 8; ++i)
        for (int j = i + 1; j < 8; ++j)
            for (int a = 0; a < 2; ++a)       // a=1 -> coord i is -1 (digit 1), else +1 (digit 3)
                for (int b = 0; b < 2; ++b) {
                    unsigned k = 0;
                    for (int d = 0; d < 8; ++d) {
                        unsigned dig = 2u;
                        if (d == i) dig = a ? 1u : 3u;
                        if (d == j) dig = b ? 1u : 3u;
                        k = k * 4u + dig;
                    }
                    key[n] = k; pi[n] = i; pj[n] = j; psi[n] = a; psj[n] = b; ++n;
                }
    for (int p = 1; p < n; ++p) { // insertion sort by key
        unsigned kk = key[p]; int a = pi[p], b = pj[p], c = psi[p], d2 = psj[p];
        int q = p - 1;
        while (q >= 0 && key[q] > kk) {
            key[q+1]=key[q]; pi[q+1]=pi[q]; pj[q+1]=pj[q]; psi[q+1]=psi[q]; psj[q+1]=psj[q]; --q;
        }
        key[q+1]=kk; pi[q+1]=a; pj[q+1]=b; psi[q+1]=c; psj[q+1]=d2;
    }
    for (int r = 0; r < n; ++r) {
        if (pi[r] < 0) t.zero_idx = (unsigned char)r;
        else t.pair_idx[(((pi[r]*8 + pj[r])*2 + psi[r])*2) + psj[r]] = (unsigned char)r;
    }
    // ---- half block: even-popcount sign masks, digit neg->1, pos->2 ----
    unsigned hkey[128] = {}; int hm[128] = {}; int hn = 0;
    for (int m = 0; m < 256; ++m) {
        int pc = 0; for (int d = 0; d < 8; ++d) pc += (m >> d) & 1;
        if (pc & 1) continue;
        unsigned k = 0;
        for (int d = 0; d < 8; ++d) k = k * 4u + (((m >> d) & 1) ? 1u : 2u);
        hkey[hn] = k; hm[hn] = m; ++hn;
    }
    for (int p = 1; p < hn; ++p) {
        unsigned kk = hkey[p]; int mm = hm[p]; int q = p - 1;
        while (q >= 0 && hkey[q] > kk) { hkey[q+1]=hkey[q]; hm[q+1]=hm[q]; --q; }
        hkey[q+1]=kk; hm[q+1]=mm;
    }
    for (int r = 0; r < hn; ++r) t.half_idx[hm[r]] = (unsigned char)(113 + r);
    return t;
}

constexpr Tables h_tab = make_tables();
__constant__ Tables g_tab = h_tab;

// MODE: 0 = Xq only; 1 = idx as uint8 bytes after Xq; 2 = idx as float after Xq
template <int MODE>
__global__ __launch_bounds__(256)
void e8_decode_kernel(const float* __restrict__ X,
                      const float* __restrict__ grid,
                      const float* __restrict__ gnorm,
                      float* __restrict__ xq_out,
                      void* __restrict__ idx_out,
                      int N)
{
    const int pt = blockIdx.x * blockDim.x + threadIdx.x;
    if (pt >= N) return;
    const int lane = threadIdx.x & 63;

    const float4* xsrc = reinterpret_cast<const float4*>(X + (size_t)pt * DIM);
    const float4 xa = xsrc[0];
    const float4 xb = xsrc[1];
    float x[8] = {xa.x, xa.y, xa.z, xa.w, xb.x, xb.y, xb.z, xb.w};

    float a[8]; uint32_t sb[8];
    #pragma unroll
    for (int d = 0; d < 8; ++d) {
        const uint32_t u = __float_as_uint(x[d]);
        sb[d] = u >> 31;
        a[d] = __uint_as_float(u & 0x7fffffffu);
    }
    uint32_t mask = 0, par = 0;
    #pragma unroll
    for (int d = 0; d < 8; ++d) { mask |= sb[d] << d; par ^= sb[d]; }
    const bool odd = (par != 0);

    // sequential sum of |x|
    float S = a[0];
    #pragma unroll
    for (int d = 1; d < 8; ++d) S += a[d];

    // min + argmin (first occurrence wins)
    float mn = a[0]; int mi = 0;
    #pragma unroll
    for (int d = 1; d < 8; ++d) { const bool lt = a[d] < mn; mn = lt ? a[d] : mn; mi = lt ? d : mi; }
    float mn2 = 3.0e38f;
    #pragma unroll
    for (int d = 0; d < 8; ++d) { const float v = (d == mi) ? 3.0e38f : a[d]; mn2 = fminf(mn2, v); }

    // top-3 of |x| (indices for top-2)
    float m1 = a[0]; int i1 = 0;
    #pragma unroll
    for (int d = 1; d < 8; ++d) { const bool gt = a[d] > m1; m1 = gt ? a[d] : m1; i1 = gt ? d : i1; }
    float m2 = -3.0e38f; int i2 = 0;
    #pragma unroll
    for (int d = 0; d < 8; ++d) {
        const float v = (d == i1) ? -3.0e38f : a[d];
        const bool gt = v > m2; m2 = gt ? v : m2; i2 = gt ? d : i2;
    }
    float m3 = -3.0e38f;
    #pragma unroll
    for (int d = 0; d < 8; ++d) {
        const float v = (d == i1 || d == i2) ? -3.0e38f : a[d];
        m3 = fmaxf(m3, v);
    }

    // ---- class champion scores (identical expressions to rounds 2-12) ----
    const float s_pair = fmaf(2.0f, m1 + m2, -2.0f);
    const float s_half = odd ? (fmaf(-2.0f, mn, S) - 2.0f) : (S - 2.0f);

    const float y01 = x[0] + x[1];
    float b[5];
    b[0] = y01 + x[2];            // {0,1,2}
    b[1] = y01 + x[4];            // {0,1,4}
    b[2] = (x[0] + x[3]) + x[4];  // {0,3,4}
    b[3] = (x[2] + x[3]) + x[4];  // {2,3,4}
    b[4] = (x[1] + x[2]) + x[3];  // {1,2,3}
    float bm = b[0]; int bi = 0;
    #pragma unroll
    for (int k = 1; k < 5; ++k) { const bool gt = b[k] > bm; bm = gt ? b[k] : bm; bi = gt ? k : bi; }
    float b2nd = -3.0e38f;
    #pragma unroll
    for (int k = 0; k < 5; ++k) { const float v = (k == bi) ? -3.0e38f : b[k]; b2nd = fmaxf(b2nd, v); }
    float tm = x[5]; int ti = 0;
    { const bool gt = x[6] > tm; tm = gt ? x[6] : tm; ti = gt ? 1 : ti; }
    { const bool gt = x[7] > tm; tm = gt ? x[7] : tm; ti = gt ? 2 : ti; }
    const float t2 = fmaxf(fminf(fmaxf(x[5], x[6]), x[7]), fminf(x[5], x[6])); // median of 3
    const float s_extra = fmaf(2.0f, bm + tm, -4.0f);

    // ---- within-class runner-ups for the tie guard ----
    const float r_pair  = fmaf(2.0f, m1 + m3, -2.0f);
    const float r_half  = odd ? (fmaf(-2.0f, mn2, S) - 2.0f)
                              : (fmaf(-2.0f, mn + mn2, S) - 2.0f);
    const float r_extra = fmaf(2.0f, fmaxf(b2nd + tm, bm + t2), -4.0f);

    // ---- codeword indices ----
    const int lo = (i1 < i2) ? i1 : i2;
    const int hi = (i1 < i2) ? i2 : i1;
    const uint32_t slo = (mask >> lo) & 1u;
    const uint32_t shi = (mask >> hi) & 1u;
    const int idx_pair  = g_tab.pair_idx[(((lo << 3) + hi) << 2) + (int)((slo << 1) | shi)];
    const uint32_t hmask = odd ? (mask ^ (1u << mi)) : mask;
    const int idx_half  = g_tab.half_idx[hmask & 255u];
    const int idx_extra = 241 + ti * 5 + bi;
    const int idx_zero  = g_tab.zero_idx;

    // ---- merge 4 candidates; track best / second-best ----
    float best = s_pair; int bidx = idx_pair; float sec = -3.0e38f;
    {
        const float s = 0.0f; const int id = idx_zero;
        const bool gt = s > best;
        const bool take = gt || (s == best && id < bidx);
        sec = fmaxf(sec, gt ? best : s);
        best = gt ? s : best;
        bidx = take ? id : bidx;
    }
    {
        const float s = s_half; const int id = idx_half;
        const bool gt = s > best;
        const bool take = gt || (s == best && id < bidx);
        sec = fmaxf(sec, gt ? best : s);
        best = gt ? s : best;
        bidx = take ? id : bidx;
    }
    {
        const float s = s_extra; const int id = idx_extra;
        const bool gt = s > best;
        const bool take = gt || (s == best && id < bidx);
        sec = fmaxf(sec, gt ? best : s);
        best = gt ? s : best;
        bidx = take ? id : bidx;
    }
    sec = fmaxf(fmaxf(sec, r_pair), fmaxf(r_half, r_extra));

    // ---- near-tie / degenerate guard: wave-cooperative rescore ----
    const bool fb = !((best - sec) > 6.4e-5f) || !(mn > 0.0f);
    uint64_t bal = __ballot(fb);
    while (bal) {
        const int src = __ffsll((unsigned long long)bal) - 1;
        bal &= bal - 1;
        float xs[8];
        #pragma unroll
        for (int d = 0; d < 8; ++d) xs[d] = __shfl(x[d], src);
        float2 xv[4];
        #pragma unroll
        for (int q = 0; q < 4; ++q)
            xv[q] = make_float2(2.0f * xs[2*q], 2.0f * xs[2*q + 1]);
        float bb = -3.4e38f; int bbi = 0;
        #pragma unroll
        for (int u = 0; u < 4; ++u) {   // c = lane*4+u, bit-identical scoring
            const int c = (lane << 2) + u;
            const float2* g2 = reinterpret_cast<const float2*>(grid + c * DIM);
            float2 acc = xv[0] * g2[0];
            acc += xv[1] * g2[1];
            acc += xv[2] * g2[2];
            acc += xv[3] * g2[3];
            const float s = (acc.x + acc.y) - gnorm[c];
            const bool gt = s > bb;
            bb = gt ? s : bb; bbi = gt ? c : bbi;
        }
        #pragma unroll
        for (int off = 32; off >= 1; off >>= 1) {  // lower index wins ties
            const float so = __shfl_xor(bb, off);
            const int   io = __shfl_xor(bbi, off);
            const bool take = (so > bb) || (so == bb && io < bbi);
            bb  = take ? so : bb;
            bbi = take ? io : bbi;
        }
        if (lane == src) bidx = bbi;
    }

    // ---- outputs: gather the winning row (L1-resident 8 KB codebook),
    //      store NON-TEMPORAL (never re-read; don't displace X from L2) ----
    const float4* gr = reinterpret_cast<const float4*>(grid + (size_t)bidx * DIM);
    const float4 q0 = gr[0];
    const float4 q1 = gr[1];
    vfloat4* dst = reinterpret_cast<vfloat4*>(xq_out + (size_t)pt * DIM);
    vfloat4 v0; v0.x = q0.x; v0.y = q0.y; v0.z = q0.z; v0.w = q0.w;
    vfloat4 v1; v1.x = q1.x; v1.y = q1.y; v1.z = q1.z; v1.w = q1.w;
    __builtin_nontemporal_store(v0, dst);
    __builtin_nontemporal_store(v1, dst + 1);
    if (MODE == 2) {
        __builtin_nontemporal_store((float)bidx,
                                    reinterpret_cast<float*>(idx_out) + pt);
    } else if (MODE == 1) {
        reinterpret_cast<uint8_t*>(idx_out)[pt] = (uint8_t)bidx;
    }
}

extern "C" void kernel_launch(void* const* d_in, const int* in_sizes, int n_in,
                              void* d_out, int out_size, void* d_ws, size_t ws_size,
                              hipStream_t stream)
{
    const float* X     = (const float*)d_in[0];
    const float* grid  = (const float*)d_in[1];
    const float* gnorm = (const float*)d_in[2];

    const int N = in_sizes[0] / DIM;

    float* xq   = (float*)d_out;
    void*  idxp = (void*)(xq + (size_t)N * DIM);

    const int blocks = (N + 255) / 256;

    const long xq_elems = (long)N * DIM;
    if ((long)out_size >= xq_elems + N) {
        e8_decode_kernel<2><<<blocks, 256, 0, stream>>>(X, grid, gnorm, xq, idxp, N);
    } else if ((long)out_size > xq_elems) {
        e8_decode_kernel<1><<<blocks, 256, 0, stream>>>(X, grid, gnorm, xq, idxp, N);
    } else {
        e8_decode_kernel<0><<<blocks, 256, 0, stream>>>(X, grid, gnorm, xq, idxp, N);
    }
}

// Round 16
// 87.379 us; speedup vs baseline: 1.1515x; 1.0061x over previous
//
#include <hip/hip_runtime.h>
#include <stdint.h>

// E8P 256-codeword quantizer, analytic decode. Round 14 kernel (second
// resubmit — GPU-acquisition timeouts; never yet run): round-13 base (PPT=1,
// wave-coop fallback, NT stores, no launch-bounds cap) + ONE change:
// arithmetic Xq reconstruction replaces the two divergent grid[bidx] gathers
// (values are exact fp32 bit patterns +-1/+-0.5/0 => bit-identical to grid
// rows; verified absmax==0 in r7/r12). Isolates the gather cost on the best
// measured structure.
//
// Falsified so far: straggler tail (fixed r4, -11us), load-issue-bound (r7
// PPT=4 neutral), low-TLP latency-bound (r12 launch-bounds cap neutral/neg).
// NT stores (r13): -1us, directionally positive.
//
// Codebook: idx 0..112 integer (zero + +-e_i+-e_j), 113..240 half (+-0.5,
// even #neg), 241..255 extra (5 bases x tails{5,6,7}).
// Near-tie guard (tau=6.4e-5 or any x_d==0): wave-cooperative rescore,
// bit-identical to the round-1 brute force (absmax==0 verified r2-r4,r7,r12,r13).

#define DIM 8
#define NCODES 256

typedef float vfloat4 __attribute__((ext_vector_type(4)));

struct Tables {
    unsigned char pair_idx[256]; // [((lo*8+hi)*2+neg_lo)*2+neg_hi]
    unsigned char half_idx[256]; // [negmask]; even-parity entries valid
    unsigned char zero_idx;
};

constexpr Tables make_tables() {
    Tables t{};
    // ---- integer block: zero + 112 pair points, ranked by lex digit key ----
    unsigned key[113] = {};
    int pi[113] = {}, pj[113] = {}, psi[113] = {}, psj[113] = {};
    int n = 0;
    { // zero vector: all digits 2 (value 0)
        unsigned k = 0;
        for (int d = 0; d < 8; ++d) k = k * 4u + 2u;
        key[n] = k; pi[n] = -1; pj[n] = -1; psi[n] = 0; psj[n] = 0; ++n;
    }
    for (int i = 0; i < 8; ++i)
        for (int j = i + 1; j < 8; ++j)
            for (int a = 0; a < 2; ++a)       // a=1 -> coord i is -1 (digit 1), else +1 (digit 3)
                for (int b = 0; b < 2; ++b) {
                    unsigned k = 0;
                    for (int d = 0; d < 8; ++d) {
                        unsigned dig = 2u;
                        if (d == i) dig = a ? 1u : 3u;
                        if (d == j) dig = b ? 1u : 3u;
                        k = k * 4u + dig;
                    }
                    key[n] = k; pi[n] = i; pj[n] = j; psi[n] = a; psj[n] = b; ++n;
                }
    for (int p = 1; p < n; ++p) { // insertion sort by key
        unsigned kk = key[p]; int a = pi[p], b = pj[p], c = psi[p], d2 = psj[p];
        int q = p - 1;
        while (q >= 0 && key[q] > kk) {
            key[q+1]=key[q]; pi[q+1]=pi[q]; pj[q+1]=pj[q]; psi[q+1]=psi[q]; psj[q+1]=psj[q]; --q;
        }
        key[q+1]=kk; pi[q+1]=a; pj[q+1]=b; psi[q+1]=c; psj[q+1]=d2;
    }
    for (int r = 0; r < n; ++r) {
        if (pi[r] < 0) t.zero_idx = (unsigned char)r;
        else t.pair_idx[(((pi[r]*8 + pj[r])*2 + psi[r])*2) + psj[r]] = (unsigned char)r;
    }
    // ---- half block: even-popcount sign masks, digit neg->1, pos->2 ----
    unsigned hkey[128] = {}; int hm[128] = {}; int hn = 0;
    for (int m = 0; m < 256; ++m) {
        int pc = 0; for (int d = 0; d < 8; ++d) pc += (m >> d) & 1;
        if (pc & 1) continue;
        unsigned k = 0;
        for (int d = 0; d < 8; ++d) k = k * 4u + (((m >> d) & 1) ? 1u : 2u);
        hkey[hn] = k; hm[hn] = m; ++hn;
    }
    for (int p = 1; p < hn; ++p) {
        unsigned kk = hkey[p]; int mm = hm[p]; int q = p - 1;
        while (q >= 0 && hkey[q] > kk) { hkey[q+1]=hkey[q]; hm[q+1]=hm[q]; --q; }
        hkey[q+1]=kk; hm[q+1]=mm;
    }
    for (int r = 0; r < hn; ++r) t.half_idx[hm[r]] = (unsigned char)(113 + r);
    return t;
}

constexpr Tables h_tab = make_tables();
__constant__ Tables g_tab = h_tab;

// MODE: 0 = Xq only; 1 = idx as uint8 bytes after Xq; 2 = idx as float after Xq
template <int MODE>
__global__ __launch_bounds__(256)
void e8_decode_kernel(const float* __restrict__ X,
                      const float* __restrict__ grid,
                      const float* __restrict__ gnorm,
                      float* __restrict__ xq_out,
                      void* __restrict__ idx_out,
                      int N)
{
    const int pt = blockIdx.x * blockDim.x + threadIdx.x;
    if (pt >= N) return;
    const int lane = threadIdx.x & 63;

    const float4* xsrc = reinterpret_cast<const float4*>(X + (size_t)pt * DIM);
    const float4 xa = xsrc[0];
    const float4 xb = xsrc[1];
    float x[8] = {xa.x, xa.y, xa.z, xa.w, xb.x, xb.y, xb.z, xb.w};

    float a[8]; uint32_t sb[8];
    #pragma unroll
    for (int d = 0; d < 8; ++d) {
        const uint32_t u = __float_as_uint(x[d]);
        sb[d] = u >> 31;
        a[d] = __uint_as_float(u & 0x7fffffffu);
    }
    uint32_t mask = 0, par = 0;
    #pragma unroll
    for (int d = 0; d < 8; ++d) { mask |= sb[d] << d; par ^= sb[d]; }
    const bool odd = (par != 0);

    // sequential sum of |x|
    float S = a[0];
    #pragma unroll
    for (int d = 1; d < 8; ++d) S += a[d];

    // min + argmin (first occurrence wins)
    float mn = a[0]; int mi = 0;
    #pragma unroll
    for (int d = 1; d < 8; ++d) { const bool lt = a[d] < mn; mn = lt ? a[d] : mn; mi = lt ? d : mi; }
    float mn2 = 3.0e38f;
    #pragma unroll
    for (int d = 0; d < 8; ++d) { const float v = (d == mi) ? 3.0e38f : a[d]; mn2 = fminf(mn2, v); }

    // top-3 of |x| (indices for top-2)
    float m1 = a[0]; int i1 = 0;
    #pragma unroll
    for (int d = 1; d < 8; ++d) { const bool gt = a[d] > m1; m1 = gt ? a[d] : m1; i1 = gt ? d : i1; }
    float m2 = -3.0e38f; int i2 = 0;
    #pragma unroll
    for (int d = 0; d < 8; ++d) {
        const float v = (d == i1) ? -3.0e38f : a[d];
        const bool gt = v > m2; m2 = gt ? v : m2; i2 = gt ? d : i2;
    }
    float m3 = -3.0e38f;
    #pragma unroll
    for (int d = 0; d < 8; ++d) {
        const float v = (d == i1 || d == i2) ? -3.0e38f : a[d];
        m3 = fmaxf(m3, v);
    }

    // ---- class champion scores (identical expressions to rounds 2-13) ----
    const float s_pair = fmaf(2.0f, m1 + m2, -2.0f);
    const float s_half = odd ? (fmaf(-2.0f, mn, S) - 2.0f) : (S - 2.0f);

    const float y01 = x[0] + x[1];
    float b[5];
    b[0] = y01 + x[2];            // {0,1,2}
    b[1] = y01 + x[4];            // {0,1,4}
    b[2] = (x[0] + x[3]) + x[4];  // {0,3,4}
    b[3] = (x[2] + x[3]) + x[4];  // {2,3,4}
    b[4] = (x[1] + x[2]) + x[3];  // {1,2,3}
    float bm = b[0]; int bi = 0;
    #pragma unroll
    for (int k = 1; k < 5; ++k) { const bool gt = b[k] > bm; bm = gt ? b[k] : bm; bi = gt ? k : bi; }
    float b2nd = -3.0e38f;
    #pragma unroll
    for (int k = 0; k < 5; ++k) { const float v = (k == bi) ? -3.0e38f : b[k]; b2nd = fmaxf(b2nd, v); }
    float tm = x[5]; int ti = 0;
    { const bool gt = x[6] > tm; tm = gt ? x[6] : tm; ti = gt ? 1 : ti; }
    { const bool gt = x[7] > tm; tm = gt ? x[7] : tm; ti = gt ? 2 : ti; }
    const float t2 = fmaxf(fminf(fmaxf(x[5], x[6]), x[7]), fminf(x[5], x[6])); // median of 3
    const float s_extra = fmaf(2.0f, bm + tm, -4.0f);

    // ---- within-class runner-ups for the tie guard ----
    const float r_pair  = fmaf(2.0f, m1 + m3, -2.0f);
    const float r_half  = odd ? (fmaf(-2.0f, mn2, S) - 2.0f)
                              : (fmaf(-2.0f, mn + mn2, S) - 2.0f);
    const float r_extra = fmaf(2.0f, fmaxf(b2nd + tm, bm + t2), -4.0f);

    // ---- codeword indices + reconstruction parameters ----
    const int lo = (i1 < i2) ? i1 : i2;
    const int hi = (i1 < i2) ? i2 : i1;
    const uint32_t slo = (mask >> lo) & 1u;
    const uint32_t shi = (mask >> hi) & 1u;
    const int idx_pair  = g_tab.pair_idx[(((lo << 3) + hi) << 2) + (int)((slo << 1) | shi)];
    const uint32_t hmask = odd ? (mask ^ (1u << mi)) : mask;
    const int idx_half  = g_tab.half_idx[hmask & 255u];
    const int idx_extra = 241 + ti * 5 + bi;
    const int idx_zero  = g_tab.zero_idx;
    // extra-row support mask: base {0,1,2}/{0,1,4}/{0,3,4}/{2,3,4}/{1,2,3} + tail bit
    const uint32_t emask = (uint32_t)((0x0E1C191307ULL >> (bi * 8)) & 0xFFu)
                         | (1u << (5 + ti));

    // ---- merge 4 candidates; track best/second-best and winning class ----
    float best = s_pair; int bidx = idx_pair; int cls = 0; float sec = -3.0e38f;
    {
        const float s = 0.0f; const int id = idx_zero;
        const bool gt = s > best;
        const bool take = gt || (s == best && id < bidx);
        sec = fmaxf(sec, gt ? best : s);
        best = gt ? s : best;
        bidx = take ? id : bidx;
        cls  = take ? 1 : cls;
    }
    {
        const float s = s_half; const int id = idx_half;
        const bool gt = s > best;
        const bool take = gt || (s == best && id < bidx);
        sec = fmaxf(sec, gt ? best : s);
        best = gt ? s : best;
        bidx = take ? id : bidx;
        cls  = take ? 2 : cls;
    }
    {
        const float s = s_extra; const int id = idx_extra;
        const bool gt = s > best;
        const bool take = gt || (s == best && id < bidx);
        sec = fmaxf(sec, gt ? best : s);
        best = gt ? s : best;
        bidx = take ? id : bidx;
        cls  = take ? 3 : cls;
    }
    sec = fmaxf(fmaxf(sec, r_pair), fmaxf(r_half, r_extra));

    // ---- near-tie / degenerate guard: wave-cooperative rescore ----
    const bool fb = !((best - sec) > 6.4e-5f) || !(mn > 0.0f);
    uint64_t bal = __ballot(fb);
    while (bal) {
        const int src = __ffsll((unsigned long long)bal) - 1;
        bal &= bal - 1;
        float xs[8];
        #pragma unroll
        for (int d = 0; d < 8; ++d) xs[d] = __shfl(x[d], src);
        float2 xv[4];
        #pragma unroll
        for (int q = 0; q < 4; ++q)
            xv[q] = make_float2(2.0f * xs[2*q], 2.0f * xs[2*q + 1]);
        float bb = -3.4e38f; int bbi = 0;
        #pragma unroll
        for (int u = 0; u < 4; ++u) {   // c = lane*4+u, bit-identical scoring
            const int c = (lane << 2) + u;
            const float2* g2 = reinterpret_cast<const float2*>(grid + c * DIM);
            float2 acc = xv[0] * g2[0];
            acc += xv[1] * g2[1];
            acc += xv[2] * g2[2];
            acc += xv[3] * g2[3];
            const float s = (acc.x + acc.y) - gnorm[c];
            const bool gt = s > bb;
            bb = gt ? s : bb; bbi = gt ? c : bbi;
        }
        #pragma unroll
        for (int off = 32; off >= 1; off >>= 1) {  // lower index wins ties
            const float so = __shfl_xor(bb, off);
            const int   io = __shfl_xor(bbi, off);
            const bool take = (so > bb) || (so == bb && io < bbi);
            bb  = take ? so : bb;
            bbi = take ? io : bbi;
        }
        if (lane == src) bidx = bbi;
    }

    // ---- arithmetic Xq reconstruction (exact: values are +-1/+-0.5/0/1) ----
    uint32_t M    = (1u << lo) | (1u << hi);
    uint32_t base = 0x3F800000u;
    uint32_t smask = mask;
    if (cls == 1) { M = 0u; }
    if (cls == 2) { M = 0xFFu; base = 0x3F000000u; smask = hmask; }
    if (cls == 3) { M = emask; base = 0x3F800000u; smask = 0u; }

    uint32_t bits[8];
    #pragma unroll
    for (int d = 0; d < 8; ++d) {
        const uint32_t mb = (M >> d) & 1u;
        const uint32_t sg = ((smask >> d) & 1u) << 31;
        bits[d] = mb ? (base | sg) : 0u;
    }
    vfloat4 v0, v1;
    v0.x = __uint_as_float(bits[0]); v0.y = __uint_as_float(bits[1]);
    v0.z = __uint_as_float(bits[2]); v0.w = __uint_as_float(bits[3]);
    v1.x = __uint_as_float(bits[4]); v1.y = __uint_as_float(bits[5]);
    v1.z = __uint_as_float(bits[6]); v1.w = __uint_as_float(bits[7]);
    if (fb) {  // rare: rescored lanes take the true grid row (exec-masked)
        const float4* gr = reinterpret_cast<const float4*>(grid + (size_t)bidx * DIM);
        const float4 q0 = gr[0];
        const float4 q1 = gr[1];
        v0.x = q0.x; v0.y = q0.y; v0.z = q0.z; v0.w = q0.w;
        v1.x = q1.x; v1.y = q1.y; v1.z = q1.z; v1.w = q1.w;
    }

    // ---- outputs: non-temporal (never re-read; don't displace X from L2) ----
    vfloat4* dst = reinterpret_cast<vfloat4*>(xq_out + (size_t)pt * DIM);
    __builtin_nontemporal_store(v0, dst);
    __builtin_nontemporal_store(v1, dst + 1);
    if (MODE == 2) {
        __builtin_nontemporal_store((float)bidx,
                                    reinterpret_cast<float*>(idx_out) + pt);
    } else if (MODE == 1) {
        reinterpret_cast<uint8_t*>(idx_out)[pt] = (uint8_t)bidx;
    }
}

extern "C" void kernel_launch(void* const* d_in, const int* in_sizes, int n_in,
                              void* d_out, int out_size, void* d_ws, size_t ws_size,
                              hipStream_t stream)
{
    const float* X     = (const float*)d_in[0];
    const float* grid  = (const float*)d_in[1];
    const float* gnorm = (const float*)d_in[2];

    const int N = in_sizes[0] / DIM;

    float* xq   = (float*)d_out;
    void*  idxp = (void*)(xq + (size_t)N * DIM);

    const int blocks = (N + 255) / 256;

    const long xq_elems = (long)N * DIM;
    if ((long)out_size >= xq_elems + N) {
        e8_decode_kernel<2><<<blocks, 256, 0, stream>>>(X, grid, gnorm, xq, idxp, N);
    } else if ((long)out_size > xq_elems) {
        e8_decode_kernel<1><<<blocks, 256, 0, stream>>>(X, grid, gnorm, xq, idxp, N);
    } else {
        e8_decode_kernel<0><<<blocks, 256, 0, stream>>>(X, grid, gnorm, xq, idxp, N);
    }
}